// Round 3
// baseline (145.391 us; speedup 1.0000x reference)
//
#include <hip/hip_runtime.h>
#include <hip/hip_bf16.h>

#define W0 0.4f
#define W1 1.6f

// 2048 blocks x 256 threads; each block handles 2048 float4 vectors (8192 elems).
// Thread processes 8 (float4,int4) pairs strided by 256, depth-2 software pipeline.

__global__ __launch_bounds__(256) void bce_reduce_kernel(
    const float4* __restrict__ in4,
    const int4* __restrict__ tg4,
    float* __restrict__ psum,
    unsigned int* __restrict__ pcnt)
{
    const int idx = blockIdx.x * 2048 + threadIdx.x;

    float4 p = in4[idx];
    int4   t = tg4[idx];

    float sum = 0.0f;
    unsigned int correct = 0;

#define ELEM(P, T)                                                    \
    {                                                                 \
        bool pos = ((T) != 0);                                        \
        float x = pos ? (P) : (1.0f - (P));                           \
        float w = pos ? W1 : W0;                                      \
        sum = __builtin_fmaf(__logf(x), w, sum);                      \
        correct += (((P) > 0.5f) == pos) ? 1u : 0u;                   \
    }

    #pragma unroll
    for (int k = 0; k < 8; ++k) {
        float4 pc = p;
        int4   tc = t;
        if (k < 7) {
            p = in4[idx + (k + 1) * 256];
            t = tg4[idx + (k + 1) * 256];
        }
        ELEM(pc.x, tc.x)
        ELEM(pc.y, tc.y)
        ELEM(pc.z, tc.z)
        ELEM(pc.w, tc.w)
    }
#undef ELEM

    // wave-64 reduction
    #pragma unroll
    for (int off = 32; off > 0; off >>= 1) {
        sum     += __shfl_down(sum, off, 64);
        correct += __shfl_down(correct, off, 64);
    }

    __shared__ float s_sum[4];
    __shared__ unsigned int s_cnt[4];
    const int lane = threadIdx.x & 63;
    const int wave = threadIdx.x >> 6;
    if (lane == 0) { s_sum[wave] = sum; s_cnt[wave] = correct; }
    __syncthreads();
    if (threadIdx.x == 0) {
        float bs = s_sum[0] + s_sum[1] + s_sum[2] + s_sum[3];
        unsigned int bc = s_cnt[0] + s_cnt[1] + s_cnt[2] + s_cnt[3];
        psum[blockIdx.x] = bs;
        pcnt[blockIdx.x] = bc;
    }
}

__global__ __launch_bounds__(1024) void bce_finalize_kernel(
    const float* __restrict__ psum,
    const unsigned int* __restrict__ pcnt,
    float* __restrict__ out, int nblocks, int n)
{
    const int tid = threadIdx.x;
    double s = 0.0;
    unsigned long long c = 0;
    for (int k = tid; k < nblocks; k += 1024) {
        s += (double)psum[k];
        c += (unsigned long long)pcnt[k];
    }
    #pragma unroll
    for (int off = 32; off > 0; off >>= 1) {
        s += __shfl_down(s, off, 64);
        c += __shfl_down(c, off, 64);
    }
    __shared__ double sh_s[16];
    __shared__ unsigned long long sh_c[16];
    const int lane = tid & 63;
    const int wave = tid >> 6;
    if (lane == 0) { sh_s[wave] = s; sh_c[wave] = c; }
    __syncthreads();
    if (tid == 0) {
        double ts = 0.0;
        unsigned long long tc = 0;
        for (int w = 0; w < 16; ++w) { ts += sh_s[w]; tc += sh_c[w]; }
        double inv_n = 1.0 / (double)n;
        out[0] = (float)(-ts * inv_n);
        out[1] = (float)((double)tc * inv_n);
    }
}

extern "C" void kernel_launch(void* const* d_in, const int* in_sizes, int n_in,
                              void* d_out, int out_size, void* d_ws, size_t ws_size,
                              hipStream_t stream) {
    const float4* in4 = (const float4*)d_in[0];
    const int4*   tg4 = (const int4*)d_in[1];
    float* out = (float*)d_out;
    int n = in_sizes[0];
    int nblocks = n >> 13;  // 8192 elems per block -> 2048 blocks for 16M

    float* psum = (float*)d_ws;
    unsigned int* pcnt = (unsigned int*)((char*)d_ws + (size_t)nblocks * sizeof(float));

    bce_reduce_kernel<<<nblocks, 256, 0, stream>>>(in4, tg4, psum, pcnt);
    bce_finalize_kernel<<<1, 1024, 0, stream>>>(psum, pcnt, out, nblocks, n);
}

// Round 4
// 144.584 us; speedup vs baseline: 1.0056x; 1.0056x over previous
//
#include <hip/hip_runtime.h>

#define W0 0.4f
#define W1 1.6f

typedef float f4v __attribute__((ext_vector_type(4)));
typedef int   i4v __attribute__((ext_vector_type(4)));

// 2048 blocks x 256 threads; each thread loads 8 float4 + 8 int4 (32 elems)
// via inline-asm global_load_dwordx4 so ALL 16 loads are in flight before the
// single vmcnt(0) drain. 16 KB outstanding per wave.

__global__ __launch_bounds__(256, 4) void bce_reduce_kernel(
    const float* __restrict__ input,
    const int* __restrict__ target,
    float* __restrict__ psum,
    unsigned int* __restrict__ pcnt)
{
    const int vbase = blockIdx.x * 2048 + threadIdx.x;  // float4-granule index
    const f4v* __restrict__ in4 = (const f4v*)input;
    const i4v* __restrict__ tg4 = (const i4v*)target;

    f4v p0, p1, p2, p3, p4, p5, p6, p7;
    i4v t0, t1, t2, t3, t4, t5, t6, t7;

#define LD(D, P) asm volatile("global_load_dwordx4 %0, %1, off" : "=v"(D) : "v"(P))
    LD(p0, in4 + vbase);
    LD(p1, in4 + vbase + 256);
    LD(p2, in4 + vbase + 512);
    LD(p3, in4 + vbase + 768);
    LD(p4, in4 + vbase + 1024);
    LD(p5, in4 + vbase + 1280);
    LD(p6, in4 + vbase + 1536);
    LD(p7, in4 + vbase + 1792);
    LD(t0, tg4 + vbase);
    LD(t1, tg4 + vbase + 256);
    LD(t2, tg4 + vbase + 512);
    LD(t3, tg4 + vbase + 768);
    LD(t4, tg4 + vbase + 1024);
    LD(t5, tg4 + vbase + 1280);
    LD(t6, tg4 + vbase + 1536);
    LD(t7, tg4 + vbase + 1792);
#undef LD

    // Drain all 16 loads; tying the values as in-outs makes every consumer
    // data-depend on this asm, so nothing reads a result before the wait.
    asm volatile("s_waitcnt vmcnt(0)"
                 : "+v"(p0), "+v"(p1), "+v"(p2), "+v"(p3),
                   "+v"(p4), "+v"(p5), "+v"(p6), "+v"(p7),
                   "+v"(t0), "+v"(t1), "+v"(t2), "+v"(t3),
                   "+v"(t4), "+v"(t5), "+v"(t6), "+v"(t7));

    float s0 = 0.0f, s1 = 0.0f;
    unsigned int c0 = 0, c1 = 0;

#define ELEM(S, C, P, T)                                              \
    {                                                                 \
        bool pos = ((T) != 0);                                        \
        float x = pos ? (P) : (1.0f - (P));                           \
        float w = pos ? W1 : W0;                                      \
        S = __builtin_fmaf(__logf(x), w, S);                          \
        C += (((P) > 0.5f) == pos) ? 1u : 0u;                         \
    }
#define VEC(S, C, P, T)                                               \
    ELEM(S, C, (P).x, (T).x) ELEM(S, C, (P).y, (T).y)                 \
    ELEM(S, C, (P).z, (T).z) ELEM(S, C, (P).w, (T).w)

    VEC(s0, c0, p0, t0)
    VEC(s1, c1, p1, t1)
    VEC(s0, c0, p2, t2)
    VEC(s1, c1, p3, t3)
    VEC(s0, c0, p4, t4)
    VEC(s1, c1, p5, t5)
    VEC(s0, c0, p6, t6)
    VEC(s1, c1, p7, t7)
#undef VEC
#undef ELEM

    float sum = s0 + s1;
    unsigned int correct = c0 + c1;

    #pragma unroll
    for (int off = 32; off > 0; off >>= 1) {
        sum     += __shfl_down(sum, off, 64);
        correct += __shfl_down(correct, off, 64);
    }

    __shared__ float s_sum[4];
    __shared__ unsigned int s_cnt[4];
    const int lane = threadIdx.x & 63;
    const int wave = threadIdx.x >> 6;
    if (lane == 0) { s_sum[wave] = sum; s_cnt[wave] = correct; }
    __syncthreads();
    if (threadIdx.x == 0) {
        float bs = s_sum[0] + s_sum[1] + s_sum[2] + s_sum[3];
        unsigned int bc = s_cnt[0] + s_cnt[1] + s_cnt[2] + s_cnt[3];
        psum[blockIdx.x] = bs;
        pcnt[blockIdx.x] = bc;
    }
}

__global__ __launch_bounds__(1024) void bce_finalize_kernel(
    const float* __restrict__ psum,
    const unsigned int* __restrict__ pcnt,
    float* __restrict__ out, int nblocks, int n)
{
    const int tid = threadIdx.x;
    double s = 0.0;
    unsigned long long c = 0;
    for (int k = tid; k < nblocks; k += 1024) {
        s += (double)psum[k];
        c += (unsigned long long)pcnt[k];
    }
    #pragma unroll
    for (int off = 32; off > 0; off >>= 1) {
        s += __shfl_down(s, off, 64);
        c += __shfl_down(c, off, 64);
    }
    __shared__ double sh_s[16];
    __shared__ unsigned long long sh_c[16];
    const int lane = tid & 63;
    const int wave = tid >> 6;
    if (lane == 0) { sh_s[wave] = s; sh_c[wave] = c; }
    __syncthreads();
    if (tid == 0) {
        double ts = 0.0;
        unsigned long long tc = 0;
        for (int w = 0; w < 16; ++w) { ts += sh_s[w]; tc += sh_c[w]; }
        double inv_n = 1.0 / (double)n;
        out[0] = (float)(-ts * inv_n);
        out[1] = (float)((double)tc * inv_n);
    }
}

extern "C" void kernel_launch(void* const* d_in, const int* in_sizes, int n_in,
                              void* d_out, int out_size, void* d_ws, size_t ws_size,
                              hipStream_t stream) {
    const float* input  = (const float*)d_in[0];
    const int*   target = (const int*)d_in[1];
    float* out = (float*)d_out;
    int n = in_sizes[0];
    // 32 elems per thread, 256 threads per block -> 8192 elems/block
    int nblocks = n >> 13;  // 2048

    float* psum = (float*)d_ws;
    unsigned int* pcnt = (unsigned int*)((char*)d_ws + (size_t)nblocks * sizeof(float));

    bce_reduce_kernel<<<nblocks, 256, 0, stream>>>(input, target, psum, pcnt);
    bce_finalize_kernel<<<1, 1024, 0, stream>>>(psum, pcnt, out, nblocks, n);
}